// Round 6
// baseline (5466.991 us; speedup 1.0000x reference)
//
#include <hip/hip_runtime.h>
#include <math.h>

// Problem constants
#define BN   128      // batch
#define TN   1440     // timesteps
#define HN   512      // hidden
#define GBn  8        // batch groups
#define BSn  16       // batches per group
#define GCn  32       // column groups
#define HCn  16       // h-cols per WG
#define WST  536      // LDS row stride in f16: 268 dw == 12 mod 32

using f16 = _Float16;
typedef f16   f16x8 __attribute__((ext_vector_type(8)));
typedef float f32x4 __attribute__((ext_vector_type(4)));
typedef unsigned int       uint32;
typedef unsigned long long u64;
typedef uint32 u32x4 __attribute__((ext_vector_type(4)));

// ws layout (bytes):
//   [0,1024)             (unused)
//   [1024,2048)          scal: [0]=half_tau, [1]=trigger
//   [2048,526336)        hbufT uint32 [2 buf][128 b][512 k]  tagged [tag8 | q24 fixed-point h]
//   [526336,1263616)     xsf f32 [128][1440]
#define OFF_SCAL 1024
#define OFF_HBUF 2048
#define OFF_XSF  (2048 + 2 * BN * HN * 4)

// ---------------- K0: scalar prep (grads -> half_tau, trigger) ----------------
__global__ void k_prep(const float* __restrict__ w_ih, float* __restrict__ scal) {
    __shared__ float ssum[4];
    float s = 0.0f;
    for (int i = threadIdx.x; i < 3 * HN * 2; i += 256) s += w_ih[i];
    for (int o = 32; o >= 1; o >>= 1) s += __shfl_down(s, o, 64);
    if ((threadIdx.x & 63) == 0) ssum[threadIdx.x >> 6] = s;
    __syncthreads();
    if (threadIdx.x == 0) {
        float tot = ssum[0] + ssum[1] + ssum[2] + ssum[3];
        float grads = tot / 3072.0f - 1.0f;
        float tau_new = 6.0f + grads * 0.1f;
        bool trig = (tau_new >= 1.0f) && (tau_new != 6.0f);
        scal[0] = rintf(tau_new * 0.5f);   // round-half-even matches jnp.round
        scal[1] = trig ? 1.0f : 0.0f;
    }
}

// ---------------- K1: NaN-fix + belief_fill (one wave per batch row) ----------------
__global__ void k_fill(const float* __restrict__ inp, const float* __restrict__ scal,
                       float* __restrict__ xsf) {
    const int b = blockIdx.x;
    const int lane = threadIdx.x;            // 0..63
    const float ht = scal[0];
    const bool trig = scal[1] != 0.0f;
    const float* xrow = inp + (size_t)b * 3 * TN;       // channel 0 = xs
    const float* mrow = xrow + 2 * TN;                   // channel 2 = mask
    const int CH = 23;                                   // 64*23 = 1472 >= 1440
    const int start = lane * CH;

    if (!trig) {
        for (int i = 0; i < CH; ++i) {
            int t = start + i;
            if (t < TN) { float x = xrow[t]; if (x != x) x = -1.0f; xsf[(size_t)b * TN + t] = x; }
        }
        return;
    }
    int pm = -1;
#pragma unroll
    for (int i = 0; i < CH; ++i) { int t = start + i; if (t < TN && mrow[t] == 1.0f) pm = t; }
    int incl = pm;
    for (int o = 1; o < 64; o <<= 1) { int v = __shfl_up(incl, o, 64); if (lane >= o) incl = max(incl, v); }
    int pexcl = __shfl_up(incl, 1, 64); if (lane == 0) pexcl = -1;
    int nm = TN;
#pragma unroll
    for (int i = CH - 1; i >= 0; --i) { int t = start + i; if (t < TN && mrow[t] == 1.0f) nm = t; }
    int incl2 = nm;
    for (int o = 1; o < 64; o <<= 1) { int v = __shfl_down(incl2, o, 64); if (lane + o < 64) incl2 = min(incl2, v); }
    int nexcl = __shfl_down(incl2, 1, 64); if (lane == 63) nexcl = TN;
    int narr[23];
    int runn = nexcl;
#pragma unroll
    for (int i = CH - 1; i >= 0; --i) {
        int t = start + i;
        if (t < TN) { if (mrow[t] == 1.0f) runn = t; narr[i] = runn; } else narr[i] = TN;
    }
    int runp = pexcl;
#pragma unroll
    for (int i = 0; i < CH; ++i) {
        int t = start + i;
        if (t >= TN) break;
        float x = xrow[t]; if (x != x) x = -1.0f;
        if (mrow[t] == 1.0f) runp = t;
        int pv = runp, nv = narr[i];
        int pc = min(max(pv, 0), TN - 1), nc = min(max(nv, 0), TN - 1);
        float xp = xrow[pc]; if (xp != xp) xp = -1.0f;
        float xn = xrow[nc]; if (xn != xn) xn = -1.0f;
        bool use_n = (nv < TN) && ((float)t >= (float)nv - ht);
        bool use_p = (pv >= 0) && ((float)t <= (float)pv + ht);
        float o = use_n ? xn : (use_p ? xp : x);
        xsf[(size_t)b * TN + t] = o;
    }
}

// ---------------- K2: persistent column-split GRU, tag-in-data (batched retry) --------
// grid 256 = 8 batch-groups x 32 col-groups; block 256 (4 waves); 1 WG/CU.
// Every h value is ONE u32 [tag8|q24] in hbufT, only ever touched with sc0sc1 (L2-bypass)
// ops -> no stale copies, no fences, no flags, no drains:
//   publish: per-thread u32 store, fire-and-forget (tag rides with payload; per-dword
//            atomicity makes each word self-validating).
//   consume: 8x global_load_dwordx4 sc0 sc1 in ONE asm block + single vmcnt(0); check all
//            32 tag bytes (~60 VALU); if any stale: s_sleep(1) and reissue the whole batch
//            (each round = ONE pipelined L3 RT -- this fixes R3's serial per-element spin).
// Step: stage(+poll) -> barrier -> MFMA -> barrier -> gate+store. 2 barriers, ~1-2 RTs.
// Weights: B-fragments (f16 hi + lo*2^11) VGPR-resident for the whole t-loop.
__global__ __launch_bounds__(256, 1) void k_gru(
    const float* __restrict__ inp, const float* __restrict__ w_ih,
    const float* __restrict__ w_hh, const float* __restrict__ b_ih,
    const float* __restrict__ b_hh, const float* __restrict__ w_fc,
    const float* __restrict__ b_fc, const float* __restrict__ xsf,
    uint32* __restrict__ hbufT, float* __restrict__ out) {
    __shared__ __align__(16) f16 sHhi[BSn * WST];
    __shared__ __align__(16) f16 sHlo[BSn * WST];
    __shared__ float sGh[3][BSn][HCn + 1];
    __shared__ float sWi0[48], sWi1[48], sBias[48];

    const int tid = threadIdx.x;
    const int gb = blockIdx.x & 7;
    const int gc = blockIdx.x >> 3;
    const int lane = tid & 63;
    const int wv   = tid >> 6;
    const int bs   = tid >> 4;        // gate-math row 0..15
    const int j    = tid & 15;
    const int bglob = gb * BSn + bs;
    const int pcol  = gc * HCn + j;
    const int frow = lane & 15;       // MFMA m (A) / n (B) index
    const int kgrp = lane >> 4;       // MFMA k-group

    if (tid < 48) {
        int gate = tid >> 4, jj = tid & 15;
        int grow = gate * HN + gc * HCn + jj;
        sWi0[tid]  = w_ih[grow * 2 + 0];
        sWi1[tid]  = w_ih[grow * 2 + 1];
        sBias[tid] = b_ih[grow] + b_hh[grow];
    }

    // one-time: weight B-fragments into VGPRs (hi + lo*2^11 split)
    f16x8 bfh[16], bfl[16];
    if (wv < 3) {
        const float* wrow = w_hh + (size_t)(wv * HN + gc * HCn + frow) * HN;
#pragma unroll
        for (int c = 0; c < 16; ++c) {
            const int k0 = (c * 4 + kgrp) * 8;
#pragma unroll
            for (int u = 0; u < 8; ++u) {
                float w = wrow[k0 + u];
                f16 hi = (f16)w;
                bfh[c][u] = hi;
                bfl[c][u] = (f16)((w - (float)hi) * 2048.0f);
            }
        }
    }
    __syncthreads();

    const f16x8* pAhi = (const f16x8*)(sHhi + frow * WST);
    const f16x8* pAlo = (const f16x8*)(sHlo + frow * WST);
    const int brow0 = tid >> 7, c4 = tid & 127;
    float h = 0.0f;

    for (int t = 0; t < TN; ++t) {
        // prefetch driving inputs (plain cached loads, reused 16-32 steps per line)
        float xsv = xsf[(size_t)bglob * TN + t];
        float mkv = inp[((size_t)bglob * 3 + 2) * TN + t];
        // 1. stage h_t: batched tagged loads; readiness check IS the tag check.
        {
            const uint32* src = hbufT + ((size_t)(t & 1) * BN + gb * BSn) * HN
                              + (size_t)brow0 * HN + c4 * 4;
            const uint32 tgw = (uint32)(t & 255) << 24;
            u32x4 r0, r1, r2, r3, r4, r5, r6, r7;
            for (;;) {
                asm volatile(
                    "global_load_dwordx4 %0, %8, off sc0 sc1\n\t"
                    "global_load_dwordx4 %1, %9, off sc0 sc1\n\t"
                    "global_load_dwordx4 %2, %10, off sc0 sc1\n\t"
                    "global_load_dwordx4 %3, %11, off sc0 sc1\n\t"
                    "global_load_dwordx4 %4, %12, off sc0 sc1\n\t"
                    "global_load_dwordx4 %5, %13, off sc0 sc1\n\t"
                    "global_load_dwordx4 %6, %14, off sc0 sc1\n\t"
                    "global_load_dwordx4 %7, %15, off sc0 sc1\n\t"
                    "s_waitcnt vmcnt(0)"
                    : "=&v"(r0), "=&v"(r1), "=&v"(r2), "=&v"(r3),
                      "=&v"(r4), "=&v"(r5), "=&v"(r6), "=&v"(r7)
                    : "v"(src), "v"(src + 1024), "v"(src + 2048), "v"(src + 3072),
                      "v"(src + 4096), "v"(src + 5120), "v"(src + 6144), "v"(src + 7168)
                    : "memory");
                uint32 m = (r0.x ^ tgw) | (r0.y ^ tgw) | (r0.z ^ tgw) | (r0.w ^ tgw)
                         | (r1.x ^ tgw) | (r1.y ^ tgw) | (r1.z ^ tgw) | (r1.w ^ tgw)
                         | (r2.x ^ tgw) | (r2.y ^ tgw) | (r2.z ^ tgw) | (r2.w ^ tgw)
                         | (r3.x ^ tgw) | (r3.y ^ tgw) | (r3.z ^ tgw) | (r3.w ^ tgw)
                         | (r4.x ^ tgw) | (r4.y ^ tgw) | (r4.z ^ tgw) | (r4.w ^ tgw)
                         | (r5.x ^ tgw) | (r5.y ^ tgw) | (r5.z ^ tgw) | (r5.w ^ tgw)
                         | (r6.x ^ tgw) | (r6.y ^ tgw) | (r6.z ^ tgw) | (r6.w ^ tgw)
                         | (r7.x ^ tgw) | (r7.y ^ tgw) | (r7.z ^ tgw) | (r7.w ^ tgw);
                if ((m & 0xFF000000u) == 0u) break;
                __builtin_amdgcn_s_sleep(1);
            }
            // unpack q24 -> f32 -> f16 hi + lo*2^11, pack pairs, write LDS
            u32x4 rr[8] = {r0, r1, r2, r3, r4, r5, r6, r7};
#pragma unroll
            for (int i = 0; i < 8; ++i) {
                int row = i * 2 + brow0;
                uint32 hp[2], lp[2];
#pragma unroll
                for (int p = 0; p < 2; ++p) {
                    uint32 va = (p == 0) ? rr[i].x : rr[i].z;
                    uint32 vb = (p == 0) ? rr[i].y : rr[i].w;
                    float fa = (float)(((int)(va << 8)) >> 8) * 0x1p-23f;
                    float fb = (float)(((int)(vb << 8)) >> 8) * 0x1p-23f;
                    f16 ha = (f16)fa, hb = (f16)fb;
                    f16 la = (f16)((fa - (float)ha) * 2048.0f);
                    f16 lb = (f16)((fb - (float)hb) * 2048.0f);
                    hp[p] = (uint32)__builtin_bit_cast(unsigned short, ha)
                          | ((uint32)__builtin_bit_cast(unsigned short, hb) << 16);
                    lp[p] = (uint32)__builtin_bit_cast(unsigned short, la)
                          | ((uint32)__builtin_bit_cast(unsigned short, lb) << 16);
                }
                *(u64*)((uint32*)(sHhi + row * WST) + c4 * 2) = (u64)hp[0] | ((u64)hp[1] << 32);
                *(u64*)((uint32*)(sHlo + row * WST) + c4 * 2) = (u64)lp[0] | ((u64)lp[1] << 32);
            }
        }
        __syncthreads();
        // 2. MFMA: wave wv computes gate tile wv (16x16), K=512, 3 split terms
        if (wv < 3) {
            f32x4 acch = {0.f, 0.f, 0.f, 0.f}, accl = {0.f, 0.f, 0.f, 0.f};
#pragma unroll
            for (int c = 0; c < 16; ++c) {
                f16x8 ah = pAhi[c * 4 + kgrp];
                f16x8 al = pAlo[c * 4 + kgrp];
                acch = __builtin_amdgcn_mfma_f32_16x16x32_f16(ah, bfh[c], acch, 0, 0, 0);
                accl = __builtin_amdgcn_mfma_f32_16x16x32_f16(ah, bfl[c], accl, 0, 0, 0);
                accl = __builtin_amdgcn_mfma_f32_16x16x32_f16(al, bfh[c], accl, 0, 0, 0);
            }
            // C/D: row=(lane>>4)*4+r (batch), col=lane&15 (j)
#pragma unroll
            for (int r = 0; r < 4; ++r)
                sGh[wv][kgrp * 4 + r][frow] = acch[r] + accl[r] * (1.0f / 2048.0f);
        }
        __syncthreads();
        // 3. exact fp32 gate math + fire-and-forget tagged publish (no drain, no flag)
        {
            float ghr = sGh[0][bs][j], ghz = sGh[1][bs][j], ghn = sGh[2][bs][j];
            float gir = xsv * sWi0[j]      + mkv * sWi1[j]      + sBias[j];
            float giz = xsv * sWi0[16 + j] + mkv * sWi1[16 + j] + sBias[16 + j];
            float gin = xsv * sWi0[32 + j] + mkv * sWi1[32 + j] + sBias[32 + j];
            float rg = 1.0f / (1.0f + __expf(-(gir + ghr)));
            float zg = 1.0f / (1.0f + __expf(-(giz + ghz)));
            float ng = tanhf(gin + rg * ghn);
            h = (1.0f - zg) * ng + zg * h;
            int q = (int)rintf(h * 8388608.0f);      // |h| < 1; +2^23 possible via rounding
            q = min(q, 8388607);
            uint32 pk = ((uint32)q & 0xFFFFFFu) | (((uint32)(t + 1) & 255u) << 24);
            __hip_atomic_store(&hbufT[((size_t)((t + 1) & 1) * BN + bglob) * HN + pcol], pk,
                               __ATOMIC_RELAXED, __HIP_MEMORY_SCOPE_AGENT);
        }
        // no third barrier: sHhi writes of step t+1 are pre-barrier-1; sGh reads above are
        // per-thread-sequential before them; MFMA(t+1) writes sGh only after barrier 1.
    }
    // 4. final FC: out[b] = sum_k h[b][k]*w_fc[k] + b_fc
    float part = h * w_fc[pcol];
#pragma unroll
    for (int o = 1; o < 16; o <<= 1) part += __shfl_xor(part, o, 64);
    if (j == 0) {
        if (gc == 0) part += b_fc[0];
        atomicAdd(&out[bglob], part);
    }
}

extern "C" void kernel_launch(void* const* d_in, const int* in_sizes, int n_in,
                              void* d_out, int out_size, void* d_ws, size_t ws_size,
                              hipStream_t stream) {
    const float* inp  = (const float*)d_in[0];
    const float* w_ih = (const float*)d_in[1];
    const float* w_hh = (const float*)d_in[2];
    const float* b_ih = (const float*)d_in[3];
    const float* b_hh = (const float*)d_in[4];
    const float* w_fc = (const float*)d_in[5];
    const float* b_fc = (const float*)d_in[6];
    float* out = (float*)d_out;
    char* ws = (char*)d_ws;
    float*  scal  = (float*)(ws + OFF_SCAL);
    uint32* hbufT = (uint32*)(ws + OFF_HBUF);
    float*  xsf   = (float*)(ws + OFF_XSF);

    // zero hbuf buf0: tag8=0 (= step-0 tag) + q24=0 (= h_0 = 0). buf1 stays 0xAA poison ->
    // tag 170 != 1, consumers spin until written. Also zero d_out (atomicAdd target).
    hipMemsetAsync(ws, 0, OFF_HBUF + BN * HN * 4, stream);
    hipMemsetAsync(d_out, 0, BN * sizeof(float), stream);
    k_prep<<<1, 256, 0, stream>>>(w_ih, scal);
    k_fill<<<BN, 64, 0, stream>>>(inp, scal, xsf);
    k_gru<<<GBn * GCn, 256, 0, stream>>>(inp, w_ih, w_hh, b_ih, b_hh, w_fc, b_fc,
                                         xsf, hbufT, out);
}